// Round 1
// baseline (176.703 us; speedup 1.0000x reference)
//
#include <hip/hip_runtime.h>
#include <stdint.h>

#define BATCH 16
#define NBOX 131072
#define NDET 100
#define CAP 1024
#define THRESH 0.9975f
#define IOU_THR 0.5f

// ---------------------------------------------------------------------------
// Kernel 1: stream-compact candidates with score >= THRESH into per-batch
// unsorted lists of packed keys: (score_bits << 32) | ~idx.
// Descending sort on this key == (score desc, idx asc) == argmax tie-break.
// ---------------------------------------------------------------------------
__global__ void compact_kernel(const float* __restrict__ scores,
                               int* __restrict__ cnt,
                               unsigned long long* __restrict__ keys) {
    int tid = blockIdx.x * blockDim.x + threadIdx.x;   // one float4 each
    const float4 s4 = reinterpret_cast<const float4*>(scores)[tid];
    int b = tid >> 15;                     // 32768 float4 per batch
    int base = (tid & 32767) << 2;         // element index within batch
    float s[4] = {s4.x, s4.y, s4.z, s4.w};
#pragma unroll
    for (int k = 0; k < 4; ++k) {
        if (s[k] >= THRESH) {
            int pos = atomicAdd(&cnt[b], 1);   // compiler wave-aggregates (m20)
            if (pos < CAP) {
                unsigned int sb = __float_as_uint(s[k]);
                unsigned int ix = (unsigned int)(base + k);
                keys[b * CAP + pos] =
                    ((unsigned long long)sb << 32) |
                    (unsigned long long)(~ix);
            }
        }
    }
}

// ---------------------------------------------------------------------------
// Suppression test, arithmetic exactly mirroring the reference (incl. the
// division) so borderline IoU comparisons can't flip.
// ---------------------------------------------------------------------------
__device__ __forceinline__ bool suppressed(const float4& c, int cc,
                                           const float4& s, int sc) {
    if (cc != sc) return false;
    float ix1 = fmaxf(s.x, c.x), iy1 = fmaxf(s.y, c.y);
    float ix2 = fminf(s.z, c.z), iy2 = fminf(s.w, c.w);
    float inter = fmaxf(ix2 - ix1, 0.f) * fmaxf(iy2 - iy1, 0.f);
    float as = (s.z - s.x) * (s.w - s.y);
    float ac = (c.z - c.x) * (c.w - c.y);
    float un = as + ac - inter;
    float iou = (un > 0.f) ? (inter / un) : 0.f;
    return iou > IOU_THR;
}

// ---------------------------------------------------------------------------
// Kernel 2: per-batch (16 blocks x 1024 threads)
//   phase 1: load keys to LDS
//   phase 2: exact rank by counting (keys unique), scatter sorted arrays,
//            gather candidate boxes/classes from global
//   phase 3: wave 0 greedy walk; selected boxes live in registers
//            (lane and lane+64 slots, max 100 selections); __ballot decides.
// ---------------------------------------------------------------------------
__global__ __launch_bounds__(1024)
void nms_kernel(const float* __restrict__ boxes,
                const int* __restrict__ classes,
                const int* __restrict__ cnt,
                const unsigned long long* __restrict__ keys,
                int* __restrict__ out) {
    __shared__ unsigned long long kx[CAP];
    __shared__ float4 sbox[CAP];
    __shared__ int scls[CAP];
    __shared__ int sidx[CAP];

    const int b = blockIdx.x;
    const int t = threadIdx.x;
    int M = cnt[b];
    if (M > CAP) M = CAP;

    if (t < M) kx[t] = keys[b * CAP + t];
    __syncthreads();

    if (t < M) {
        unsigned long long mykey = kx[t];
        int r = 0;
        for (int j = 0; j < M; ++j) r += (kx[j] > mykey);  // LDS broadcast
        int idx = (int)(~(unsigned int)mykey);
        sidx[r] = idx;
        sbox[r] = reinterpret_cast<const float4*>(boxes)[b * NBOX + idx];
        scls[r] = classes[b * NBOX + idx];
    }
    __syncthreads();

    if (t < 64) {   // wave 0 only; no barriers below (no divergent-barrier UB)
        const int lane = t;
        int nsel = 0;
        float4 b0 = make_float4(0.f, 0.f, 0.f, 0.f), b1 = b0;
        int c0 = -1, c1 = -1;

        float4 cb = b0; int cc = 0, ci = 0;
        if (M > 0) { cb = sbox[0]; cc = scls[0]; ci = sidx[0]; }

        for (int i = 0; i < M && nsel < NDET; ++i) {
            // prefetch next candidate (hides LDS latency behind the IoU test)
            float4 nb = cb; int nc = cc, ni = ci;
            if (i + 1 < M) { nb = sbox[i + 1]; nc = scls[i + 1]; ni = sidx[i + 1]; }

            bool sup = false;
            if (lane < nsel)      sup |= suppressed(cb, cc, b0, c0);
            if (lane + 64 < nsel) sup |= suppressed(cb, cc, b1, c1);

            if (__ballot(sup) == 0ULL) {
                if (nsel < 64) { if (lane == nsel)      { b0 = cb; c0 = cc; } }
                else           { if (lane == nsel - 64) { b1 = cb; c1 = cc; } }
                if (lane == 0) out[b * NDET + nsel] = ci;
                ++nsel;
            }
            cb = nb; cc = nc; ci = ni;
        }
        for (int k = nsel + lane; k < NDET; k += 64) out[b * NDET + k] = -1;
    }
}

// ---------------------------------------------------------------------------
extern "C" void kernel_launch(void* const* d_in, const int* in_sizes, int n_in,
                              void* d_out, int out_size, void* d_ws, size_t ws_size,
                              hipStream_t stream) {
    (void)in_sizes; (void)n_in; (void)out_size; (void)ws_size;
    const float* scores  = (const float*)d_in[0];
    const float* boxes   = (const float*)d_in[1];
    const int*   classes = (const int*)d_in[2];
    int* out = (int*)d_out;

    int* cnt = (int*)d_ws;                                        // 16 ints
    unsigned long long* keys =
        (unsigned long long*)((char*)d_ws + 256);                 // B*CAP u64

    hipMemsetAsync(cnt, 0, 256, stream);   // ws is poisoned 0xAA every call
    compact_kernel<<<2048, 256, 0, stream>>>(scores, cnt, keys);
    nms_kernel<<<BATCH, 1024, 0, stream>>>(boxes, classes, cnt, keys, out);
}

// Round 2
// 118.560 us; speedup vs baseline: 1.4904x; 1.4904x over previous
//
#include <hip/hip_runtime.h>
#include <stdint.h>

#define BATCH 16
#define NBOX 131072
#define NDET 100
#define CAP 1024
#define THRESH 0.9975f
#define IOU_THR 0.5f
#define CNT_STRIDE 64   // ints; 256 B between per-batch counters (own cache line)

// ---------------------------------------------------------------------------
// Kernel 1: stream-compact candidates with score >= THRESH into per-batch
// unsorted lists of packed keys: (score_bits << 32) | ~idx.
// Descending sort on this key == (score desc, idx asc) == argmax tie-break.
// Atomic discipline: ONE atomicAdd per block (512 total, 32 per counter,
// counters on separate cache lines) — round 1 showed per-lane same-line
// atomics across XCDs serialize at ~13 ns each (63.5 us for ~5K atomics).
// ---------------------------------------------------------------------------
__global__ __launch_bounds__(1024)
void compact_kernel(const float* __restrict__ scores,
                    int* __restrict__ cnt,
                    unsigned long long* __restrict__ keys) {
    const int b      = blockIdx.x >> 5;        // 32 blocks per batch
    const int blkInB = blockIdx.x & 31;        // each covers 4096 elements
    const int t      = threadIdx.x;            // 0..1023
    const int wave   = t >> 6;
    const int lane   = t & 63;

    const int e4   = blkInB * 1024 + t;        // float4 index within batch
    const float4 s4 = reinterpret_cast<const float4*>(scores)[b * 32768 + e4];

    bool p[4] = { s4.x >= THRESH, s4.y >= THRESH, s4.z >= THRESH, s4.w >= THRESH };
    unsigned long long m[4];
#pragma unroll
    for (int k = 0; k < 4; ++k) m[k] = __ballot(p[k]);

    int wcount = (int)(__popcll(m[0]) + __popcll(m[1]) + __popcll(m[2]) + __popcll(m[3]));

    __shared__ int wcnt[16];
    __shared__ int wbase[16];
    __shared__ int blockbase;
    if (lane == 0) wcnt[wave] = wcount;
    __syncthreads();
    if (t == 0) {
        int s = 0;
#pragma unroll
        for (int w = 0; w < 16; ++w) { wbase[w] = s; s += wcnt[w]; }
        blockbase = (s > 0) ? atomicAdd(&cnt[b * CNT_STRIDE], s) : 0;
    }
    __syncthreads();

    int base = blockbase + wbase[wave];
    const unsigned long long below = (lane == 0) ? 0ULL : ((1ULL << lane) - 1ULL);
    const float s[4] = { s4.x, s4.y, s4.z, s4.w };
    int off = 0;
#pragma unroll
    for (int k = 0; k < 4; ++k) {
        if (p[k]) {
            int pos = base + off + (int)__popcll(m[k] & below);
            if (pos < CAP) {
                unsigned int sb = __float_as_uint(s[k]);
                unsigned int ix = (unsigned int)(e4 * 4 + k);
                keys[b * CAP + pos] = ((unsigned long long)sb << 32) |
                                      (unsigned long long)(~ix);
            }
        }
        off += (int)__popcll(m[k]);
    }
}

// ---------------------------------------------------------------------------
// Suppression test, arithmetic exactly mirroring the reference (incl. the
// division) so borderline IoU comparisons can't flip.
// ---------------------------------------------------------------------------
__device__ __forceinline__ bool suppressed(const float4& c, int cc,
                                           const float4& s, int sc) {
    if (cc != sc) return false;
    float ix1 = fmaxf(s.x, c.x), iy1 = fmaxf(s.y, c.y);
    float ix2 = fminf(s.z, c.z), iy2 = fminf(s.w, c.w);
    float inter = fmaxf(ix2 - ix1, 0.f) * fmaxf(iy2 - iy1, 0.f);
    float as = (s.z - s.x) * (s.w - s.y);
    float ac = (c.z - c.x) * (c.w - c.y);
    float un = as + ac - inter;
    float iou = (un > 0.f) ? (inter / un) : 0.f;
    return iou > IOU_THR;
}

// ---------------------------------------------------------------------------
// Kernel 2: per-batch (16 blocks x 1024 threads)
//   phase 1: load keys to LDS
//   phase 2: exact rank by counting (keys unique), scatter sorted arrays,
//            gather candidate boxes/classes from global
//   phase 3: wave 0 greedy walk; selected boxes live in registers
//            (lane and lane+64 slots, max 100 selections); __ballot decides.
// ---------------------------------------------------------------------------
__global__ __launch_bounds__(1024)
void nms_kernel(const float* __restrict__ boxes,
                const int* __restrict__ classes,
                const int* __restrict__ cnt,
                const unsigned long long* __restrict__ keys,
                int* __restrict__ out) {
    __shared__ unsigned long long kx[CAP];
    __shared__ float4 sbox[CAP];
    __shared__ int scls[CAP];
    __shared__ int sidx[CAP];

    const int b = blockIdx.x;
    const int t = threadIdx.x;
    int M = cnt[b * CNT_STRIDE];
    if (M > CAP) M = CAP;

    if (t < M) kx[t] = keys[b * CAP + t];
    __syncthreads();

    if (t < M) {
        unsigned long long mykey = kx[t];
        int r = 0;
        for (int j = 0; j < M; ++j) r += (kx[j] > mykey);  // LDS broadcast
        int idx = (int)(~(unsigned int)mykey);
        sidx[r] = idx;
        sbox[r] = reinterpret_cast<const float4*>(boxes)[b * NBOX + idx];
        scls[r] = classes[b * NBOX + idx];
    }
    __syncthreads();

    if (t < 64) {   // wave 0 only; no barriers below (no divergent-barrier UB)
        const int lane = t;
        int nsel = 0;
        float4 b0 = make_float4(0.f, 0.f, 0.f, 0.f), b1 = b0;
        int c0 = -1, c1 = -1;

        float4 cb = b0; int cc = 0, ci = 0;
        if (M > 0) { cb = sbox[0]; cc = scls[0]; ci = sidx[0]; }

        for (int i = 0; i < M && nsel < NDET; ++i) {
            // prefetch next candidate (hides LDS latency behind the IoU test)
            float4 nb = cb; int nc = cc, ni = ci;
            if (i + 1 < M) { nb = sbox[i + 1]; nc = scls[i + 1]; ni = sidx[i + 1]; }

            bool sup = false;
            if (lane < nsel)      sup |= suppressed(cb, cc, b0, c0);
            if (lane + 64 < nsel) sup |= suppressed(cb, cc, b1, c1);

            if (__ballot(sup) == 0ULL) {
                if (nsel < 64) { if (lane == nsel)      { b0 = cb; c0 = cc; } }
                else           { if (lane == nsel - 64) { b1 = cb; c1 = cc; } }
                if (lane == 0) out[b * NDET + nsel] = ci;
                ++nsel;
            }
            cb = nb; cc = nc; ci = ni;
        }
        for (int k = nsel + lane; k < NDET; k += 64) out[b * NDET + k] = -1;
    }
}

// ---------------------------------------------------------------------------
extern "C" void kernel_launch(void* const* d_in, const int* in_sizes, int n_in,
                              void* d_out, int out_size, void* d_ws, size_t ws_size,
                              hipStream_t stream) {
    (void)in_sizes; (void)n_in; (void)out_size; (void)ws_size;
    const float* scores  = (const float*)d_in[0];
    const float* boxes   = (const float*)d_in[1];
    const int*   classes = (const int*)d_in[2];
    int* out = (int*)d_out;

    int* cnt = (int*)d_ws;                                        // padded counters
    unsigned long long* keys =
        (unsigned long long*)((char*)d_ws + BATCH * CNT_STRIDE * sizeof(int));

    hipMemsetAsync(cnt, 0, BATCH * CNT_STRIDE * sizeof(int), stream);
    compact_kernel<<<BATCH * 32, 1024, 0, stream>>>(scores, cnt, keys);
    nms_kernel<<<BATCH, 1024, 0, stream>>>(boxes, classes, cnt, keys, out);
}